// Round 1
// baseline (2375.238 us; speedup 1.0000x reference)
//
#include <hip/hip_runtime.h>
#include <hip/hip_bf16.h>

#define D_DIM 128
#define NH_DIM 8

// ---- order-preserving float<->uint encoding for atomicMax ----
__device__ __forceinline__ unsigned enc_f(float f){
    unsigned u = __float_as_uint(f);
    return (u & 0x80000000u) ? ~u : (u | 0x80000000u);
}
__device__ __forceinline__ float dec_f(unsigned u){
    return __uint_as_float((u & 0x80000000u) ? (u & 0x7fffffffu) : ~u);
}

// M[k*16+c]: c<8 -> (W1 @ W4^T)[k,c], c>=8 -> (W2 @ W4^T)[k,c-8]; w34[h] = W3 . W4[h]
__global__ void k_prep(const float* __restrict__ W1, const float* __restrict__ W2,
                       const float* __restrict__ W3, const float* __restrict__ W4,
                       float* __restrict__ M, float* __restrict__ w34){
    int t = blockIdx.x * blockDim.x + threadIdx.x;
    if (t < 2048){
        int k = t >> 4, c = t & 15;
        const float* Wrow  = (c < 8 ? W1 : W2) + k * D_DIM;
        const float* W4row = W4 + (c & 7) * D_DIM;
        float acc = 0.f;
        #pragma unroll 8
        for (int j = 0; j < D_DIM; ++j) acc += Wrow[j] * W4row[j];
        M[t] = acc;
    } else if (t < 2056){
        int h = t - 2048;
        const float* W4row = W4 + h * D_DIM;
        float acc = 0.f;
        #pragma unroll 8
        for (int j = 0; j < D_DIM; ++j) acc += W4row[j] * W3[j];
        w34[h] = acc;
    }
}

// A[n*16+c] = H[n,:] . M[:,c]   (c<8: dst-side term A1, c>=8: src-side term A2)
__global__ void k_A(const float* __restrict__ H, const float* __restrict__ M,
                    float* __restrict__ A, int N){
    int t = blockIdx.x * blockDim.x + threadIdx.x;
    if (t >= N * 16) return;
    int n = t >> 4, c = t & 15;
    const float* Hrow = H + (size_t)n * D_DIM;
    const float* Mc   = M + c;
    float acc = 0.f;
    #pragma unroll 8
    for (int k = 0; k < D_DIM; ++k) acc += Hrow[k] * Mc[k * 16];
    A[t] = acc;
}

// Y = X @ W  (X: N x 128, W: 128 x 128). 4 rows / block, 128 threads.
__global__ void k_rowgemm(const float* __restrict__ X, const float* __restrict__ W,
                          float* __restrict__ Y, int N){
    __shared__ float xs[4][D_DIM];
    int tid = threadIdx.x;
    int r0  = blockIdx.x * 4;
    #pragma unroll
    for (int r = 0; r < 4; ++r){
        int n = r0 + r;
        xs[r][tid] = (n < N) ? X[(size_t)n * D_DIM + tid] : 0.f;
    }
    __syncthreads();
    float a0 = 0.f, a1 = 0.f, a2 = 0.f, a3 = 0.f;
    #pragma unroll 4
    for (int k = 0; k < D_DIM; ++k){
        float w = W[k * D_DIM + tid];
        a0 += xs[0][k] * w; a1 += xs[1][k] * w;
        a2 += xs[2][k] * w; a3 += xs[3][k] * w;
    }
    if (r0 + 0 < N) Y[(size_t)(r0 + 0) * D_DIM + tid] = a0;
    if (r0 + 1 < N) Y[(size_t)(r0 + 1) * D_DIM + tid] = a1;
    if (r0 + 2 < N) Y[(size_t)(r0 + 2) * D_DIM + tid] = a2;
    if (r0 + 3 < N) Y[(size_t)(r0 + 3) * D_DIM + tid] = a3;
}

__device__ __forceinline__ void edge_logits(const float* __restrict__ A,
                                            const float* __restrict__ w34,
                                            int s, int d, float p, float dv,
                                            float* __restrict__ l){
    const float4* a1p = (const float4*)(A + (size_t)d * 16);
    const float4* a2p = (const float4*)(A + (size_t)s * 16 + 8);
    float4 a1l = a1p[0], a1h = a1p[1];
    float4 a2l = a2p[0], a2h = a2p[1];
    float s1[8] = {a1l.x, a1l.y, a1l.z, a1l.w, a1h.x, a1h.y, a1h.z, a1h.w};
    float s2[8] = {a2l.x, a2l.y, a2l.z, a2l.w, a2h.x, a2h.y, a2h.z, a2h.w};
    #pragma unroll
    for (int h = 0; h < 8; ++h){
        float v = s1[h] + s2[h] + p * w34[h] + dv;
        l[h] = (v >= 0.f) ? v : 0.2f * v;
    }
}

__global__ void k_logit_max(const int* __restrict__ ei, const float* __restrict__ P,
                            const float* __restrict__ det, const float* __restrict__ A,
                            const float* __restrict__ w34, unsigned* __restrict__ m,
                            int E){
    int e = blockIdx.x * blockDim.x + threadIdx.x;
    if (e >= E) return;
    int s = ei[e], d = ei[E + e];
    float l[8];
    edge_logits(A, w34, s, d, P[e], det[e], l);
    #pragma unroll
    for (int h = 0; h < 8; ++h)
        atomicMax(&m[(size_t)d * NH_DIM + h], enc_f(l[h]));
}

__global__ void k_expsum(const int* __restrict__ ei, const float* __restrict__ P,
                         const float* __restrict__ det, const float* __restrict__ A,
                         const float* __restrict__ w34, const unsigned* __restrict__ m,
                         float* __restrict__ sarr, int E){
    int e = blockIdx.x * blockDim.x + threadIdx.x;
    if (e >= E) return;
    int s = ei[e], d = ei[E + e];
    float l[8];
    edge_logits(A, w34, s, d, P[e], det[e], l);
    #pragma unroll
    for (int h = 0; h < 8; ++h){
        float mm = dec_f(m[(size_t)d * NH_DIM + h]);
        atomicAdd(&sarr[(size_t)d * NH_DIM + h], __expf(l[h] - mm));
    }
}

// 32 threads per edge; thread g handles dims [g*4, g*4+4)  (head = g>>2)
__global__ void k_aggregate(const int* __restrict__ ei, const float* __restrict__ P,
                            const float* __restrict__ det, const float* __restrict__ A,
                            const float* __restrict__ w34, const unsigned* __restrict__ m,
                            const float* __restrict__ sarr, const float* __restrict__ V,
                            float* __restrict__ agg, int E){
    int t = blockIdx.x * blockDim.x + threadIdx.x;
    int e = t >> 5;
    if (e >= E) return;
    int g  = t & 31;
    int h  = g >> 2;     // head whose alpha this thread consumes
    int hc = g & 7;      // head this thread computes alpha for
    int s = ei[e], d = ei[E + e];
    float p = P[e], dv = det[e];

    float l = A[(size_t)d * 16 + hc] + A[(size_t)s * 16 + 8 + hc] + p * w34[hc] + dv;
    l = (l >= 0.f) ? l : 0.2f * l;
    float mm = dec_f(m[(size_t)d * NH_DIM + hc]);
    float sv = sarr[(size_t)d * NH_DIM + hc];
    float al = __expf(l - mm) / (sv + 1e-12f);
    float alpha = __shfl(al, h, 32);

    const float4 v4 = *(const float4*)(V + (size_t)s * D_DIM + g * 4);
    float* ap = agg + (size_t)d * D_DIM + g * 4;
    atomicAdd(ap + 0, alpha * v4.x);
    atomicAdd(ap + 1, alpha * v4.y);
    atomicAdd(ap + 2, alpha * v4.z);
    atomicAdd(ap + 3, alpha * v4.w);
}

// out = LN(agg@Wout + H@Wres + b_out + b_res) * gamma + beta; 4 rows/block, 128 thr
__global__ void k_final(const float* __restrict__ agg, const float* __restrict__ H,
                        const float* __restrict__ Wout, const float* __restrict__ Wres,
                        const float* __restrict__ b_out, const float* __restrict__ b_res,
                        const float* __restrict__ gamma, const float* __restrict__ beta,
                        float* __restrict__ out, int N){
    __shared__ float as_[4][D_DIM];
    __shared__ float hs[4][D_DIM];
    __shared__ float redS[2], redQ[2];
    int tid = threadIdx.x;
    int r0  = blockIdx.x * 4;
    #pragma unroll
    for (int r = 0; r < 4; ++r){
        int n = r0 + r;
        as_[r][tid] = (n < N) ? agg[(size_t)n * D_DIM + tid] : 0.f;
        hs[r][tid]  = (n < N) ? H[(size_t)n * D_DIM + tid]   : 0.f;
    }
    __syncthreads();
    float bias = b_out[tid] + b_res[tid];
    float acc[4] = {bias, bias, bias, bias};
    #pragma unroll 4
    for (int k = 0; k < D_DIM; ++k){
        float wo = Wout[k * D_DIM + tid];
        float wr = Wres[k * D_DIM + tid];
        #pragma unroll
        for (int r = 0; r < 4; ++r) acc[r] += as_[r][k] * wo + hs[r][k] * wr;
    }
    int lane = tid & 63, w = tid >> 6;
    float g = gamma[tid], b = beta[tid];
    #pragma unroll
    for (int r = 0; r < 4; ++r){
        float val = acc[r];
        float v = val, v2 = val * val;
        #pragma unroll
        for (int off = 32; off > 0; off >>= 1){
            v  += __shfl_down(v,  off);
            v2 += __shfl_down(v2, off);
        }
        if (lane == 0){ redS[w] = v; redQ[w] = v2; }
        __syncthreads();
        float mu = (redS[0] + redS[1]) * (1.f / 128.f);
        float ms = (redQ[0] + redQ[1]) * (1.f / 128.f);
        float rstd = rsqrtf(ms - mu * mu + 1e-5f);
        int n = r0 + r;
        if (n < N) out[(size_t)n * D_DIM + tid] = (val - mu) * rstd * g + b;
        __syncthreads();
    }
}

extern "C" void kernel_launch(void* const* d_in, const int* in_sizes, int n_in,
                              void* d_out, int out_size, void* d_ws, size_t ws_size,
                              hipStream_t stream){
    const float* H     = (const float*)d_in[0];
    const int*   ei    = (const int*)  d_in[1];
    const float* P     = (const float*)d_in[2];
    const float* det   = (const float*)d_in[3];
    const float* W1    = (const float*)d_in[4];
    const float* W2    = (const float*)d_in[5];
    const float* W3    = (const float*)d_in[6];
    const float* W4    = (const float*)d_in[7];
    const float* Wv    = (const float*)d_in[8];
    const float* Wout  = (const float*)d_in[9];
    const float* b_out = (const float*)d_in[10];
    const float* Wres  = (const float*)d_in[11];
    const float* b_res = (const float*)d_in[12];
    const float* gamma = (const float*)d_in[13];
    const float* beta  = (const float*)d_in[14];
    float* out = (float*)d_out;

    int N = in_sizes[0] / D_DIM;
    int E = in_sizes[2];

    float* ws = (float*)d_ws;
    size_t off = 0;
    float*    M    = ws + off; off += 2048;
    float*    w34  = ws + off; off += 8;
    float*    A    = ws + off; off += (size_t)N * 16;
    float*    V    = ws + off; off += (size_t)N * D_DIM;
    unsigned* m    = (unsigned*)(ws + off); off += (size_t)N * NH_DIM;
    float*    sarr = ws + off; off += (size_t)N * NH_DIM;
    float*    agg  = ws + off; off += (size_t)N * D_DIM;

    // zero m (enc(-inf) < 0+eps for all reachable values), s, agg in one shot
    hipMemsetAsync(m, 0, (size_t)N * (2 * NH_DIM + D_DIM) * sizeof(float), stream);

    k_prep<<<9, 256, 0, stream>>>(W1, W2, W3, W4, M, w34);
    k_A<<<(N * 16 + 255) / 256, 256, 0, stream>>>(H, M, A, N);
    k_rowgemm<<<(N + 3) / 4, 128, 0, stream>>>(H, Wv, V, N);
    k_logit_max<<<(E + 255) / 256, 256, 0, stream>>>(ei, P, det, A, w34, m, E);
    k_expsum<<<(E + 255) / 256, 256, 0, stream>>>(ei, P, det, A, w34, m, sarr, E);
    long long tagg = (long long)E * 32;
    k_aggregate<<<(int)((tagg + 255) / 256), 256, 0, stream>>>(ei, P, det, A, w34, m,
                                                               sarr, V, agg, E);
    k_final<<<(N + 3) / 4, 128, 0, stream>>>(agg, H, Wout, Wres, b_out, b_res,
                                             gamma, beta, out, N);
}

// Round 2
// 477.733 us; speedup vs baseline: 4.9719x; 4.9719x over previous
//
#include <hip/hip_runtime.h>
#include <hip/hip_bf16.h>

#define D_DIM 128
#define NH_DIM 8

// M[k*16+c]: c<8 -> (W1 @ W4^T)[k,c], c>=8 -> (W2 @ W4^T)[k,c-8]; w34[h] = W3 . W4[h]
__global__ void k_prep(const float* __restrict__ W1, const float* __restrict__ W2,
                       const float* __restrict__ W3, const float* __restrict__ W4,
                       float* __restrict__ M, float* __restrict__ w34){
    int t = blockIdx.x * blockDim.x + threadIdx.x;
    if (t < 2048){
        int k = t >> 4, c = t & 15;
        const float* Wrow  = (c < 8 ? W1 : W2) + k * D_DIM;
        const float* W4row = W4 + (c & 7) * D_DIM;
        float acc = 0.f;
        #pragma unroll 8
        for (int j = 0; j < D_DIM; ++j) acc += Wrow[j] * W4row[j];
        M[t] = acc;
    } else if (t < 2056){
        int h = t - 2048;
        const float* W4row = W4 + h * D_DIM;
        float acc = 0.f;
        #pragma unroll 8
        for (int j = 0; j < D_DIM; ++j) acc += W4row[j] * W3[j];
        w34[h] = acc;
    }
}

// A[n*16+c] = H[n,:] . M[:,c]   (c<8: dst-side term A1, c>=8: src-side term A2)
__global__ void k_A(const float* __restrict__ H, const float* __restrict__ M,
                    float* __restrict__ A, int N){
    int t = blockIdx.x * blockDim.x + threadIdx.x;
    if (t >= N * 16) return;
    int n = t >> 4, c = t & 15;
    const float* Hrow = H + (size_t)n * D_DIM;
    const float* Mc   = M + c;
    float acc = 0.f;
    #pragma unroll 8
    for (int k = 0; k < D_DIM; ++k) acc += Hrow[k] * Mc[k * 16];
    A[t] = acc;
}

// Y = X @ W  (X: N x 128, W: 128 x 128). 4 rows / block, 128 threads.
__global__ void k_rowgemm(const float* __restrict__ X, const float* __restrict__ W,
                          float* __restrict__ Y, int N){
    __shared__ float xs[4][D_DIM];
    int tid = threadIdx.x;
    int r0  = blockIdx.x * 4;
    #pragma unroll
    for (int r = 0; r < 4; ++r){
        int n = r0 + r;
        xs[r][tid] = (n < N) ? X[(size_t)n * D_DIM + tid] : 0.f;
    }
    __syncthreads();
    float a0 = 0.f, a1 = 0.f, a2 = 0.f, a3 = 0.f;
    #pragma unroll 4
    for (int k = 0; k < D_DIM; ++k){
        float w = W[k * D_DIM + tid];
        a0 += xs[0][k] * w; a1 += xs[1][k] * w;
        a2 += xs[2][k] * w; a3 += xs[3][k] * w;
    }
    if (r0 + 0 < N) Y[(size_t)(r0 + 0) * D_DIM + tid] = a0;
    if (r0 + 1 < N) Y[(size_t)(r0 + 1) * D_DIM + tid] = a1;
    if (r0 + 2 < N) Y[(size_t)(r0 + 2) * D_DIM + tid] = a2;
    if (r0 + 3 < N) Y[(size_t)(r0 + 3) * D_DIM + tid] = a3;
}

// -------- CSR build --------
__global__ void k_deg(const int* __restrict__ ei, int* __restrict__ deg, int E){
    int e = blockIdx.x * blockDim.x + threadIdx.x;
    if (e >= E) return;
    atomicAdd(&deg[ei[E + e]], 1);
}

__device__ __forceinline__ int block_excl_scan_i(int v, int tid, int* wsum){
    int lane = tid & 63, w = tid >> 6;
    int x = v;
    #pragma unroll
    for (int off = 1; off < 64; off <<= 1){
        int y = __shfl_up(x, off);
        if (lane >= off) x += y;
    }
    if (lane == 63) wsum[w] = x;
    __syncthreads();
    int wofs = 0;
    for (int i = 0; i < w; ++i) wofs += wsum[i];
    int r = wofs + x - v;
    __syncthreads();
    return r;
}

__global__ void k_scan1(const int* __restrict__ deg, int* __restrict__ bsum, int N){
    int i = blockIdx.x * 256 + threadIdx.x;
    int v = (i < N) ? deg[i] : 0;
    int lane = threadIdx.x & 63, w = threadIdx.x >> 6;
    #pragma unroll
    for (int off = 32; off > 0; off >>= 1) v += __shfl_down(v, off);
    __shared__ int ws_[4];
    if (lane == 0) ws_[w] = v;
    __syncthreads();
    if (threadIdx.x == 0) bsum[blockIdx.x] = ws_[0] + ws_[1] + ws_[2] + ws_[3];
}

__global__ void k_scan2(const int* __restrict__ bsum, int* __restrict__ boff, int nb){
    __shared__ int wsum[4];
    __shared__ int carry_s;
    if (threadIdx.x == 0) carry_s = 0;
    __syncthreads();
    for (int start = 0; start < nb; start += 256){
        int i = start + threadIdx.x;
        int v = (i < nb) ? bsum[i] : 0;
        int ex = block_excl_scan_i(v, threadIdx.x, wsum);
        int c = carry_s;
        if (i < nb) boff[i] = c + ex;
        __syncthreads();
        if (threadIdx.x == 255) carry_s = c + ex + v;
        __syncthreads();
    }
}

__global__ void k_scan3(const int* __restrict__ deg, const int* __restrict__ boff,
                        int* __restrict__ offsets, int N){
    __shared__ int wsum[4];
    int i = blockIdx.x * 256 + threadIdx.x;
    int v = (i < N) ? deg[i] : 0;
    int ex = block_excl_scan_i(v, threadIdx.x, wsum);
    if (i < N) offsets[i] = boff[blockIdx.x] + ex;
}

__global__ void k_scatter(const int* __restrict__ ei, const float* __restrict__ P,
                          const float* __restrict__ det, const int* __restrict__ offsets,
                          int* __restrict__ cursor, int* __restrict__ ssrc,
                          float* __restrict__ sp, float* __restrict__ sdv, int E){
    int e = blockIdx.x * blockDim.x + threadIdx.x;
    if (e >= E) return;
    int d = ei[E + e];
    int idx = offsets[d] + atomicAdd(&cursor[d], 1);
    ssrc[idx] = ei[e];
    sp[idx]   = P[e];
    sdv[idx]  = det[e];
}

// -------- per-node softmax + aggregation: one wave per dst node, no fp atomics --------
__global__ void k_agg(const int* __restrict__ offsets, const int* __restrict__ deg,
                      const int* __restrict__ ssrc, const float* __restrict__ sp,
                      const float* __restrict__ sdv, const float* __restrict__ A,
                      const float* __restrict__ w34, const float* __restrict__ V,
                      float* __restrict__ agg, int N){
    int node = blockIdx.x * 4 + (threadIdx.x >> 6);
    if (node >= N) return;
    int lane = threadIdx.x & 63;
    int base = offsets[node];
    int dg   = deg[node];

    // phase 1: online softmax; lane handles head h1 = lane&7, edges (lane>>3)+k*8
    int h1 = lane & 7;
    float a1   = A[(size_t)node * 16 + h1];
    float w34h = w34[h1];
    float mloc = -1e30f, sloc = 0.f;
    for (int j = lane >> 3; j < dg; j += 8){
        int   s = ssrc[base + j];
        float l = a1 + A[(size_t)s * 16 + 8 + h1] + sp[base + j] * w34h + sdv[base + j];
        l = (l >= 0.f) ? l : 0.2f * l;
        if (l > mloc){ sloc = sloc * __expf(mloc - l) + 1.f; mloc = l; }
        else         { sloc += __expf(l - mloc); }
    }
    #pragma unroll
    for (int off = 8; off < 64; off <<= 1){
        float mo = __shfl_xor(mloc, off);
        float so = __shfl_xor(sloc, off);
        float mn = fmaxf(mloc, mo);
        sloc = sloc * __expf(mloc - mn) + so * __expf(mo - mn);
        mloc = mn;
    }

    // phase 2: lane owns dims {lane*2, lane*2+1}; its head h2 = lane>>3
    int h2 = lane >> 3;
    float mf = __shfl(mloc, h2);
    float sf = __shfl(sloc, h2);
    float inv = 1.f / (sf + 1e-12f);
    float a1h = A[(size_t)node * 16 + h2];
    float w3h = w34[h2];
    float ax = 0.f, ay = 0.f;
    for (int j = 0; j < dg; ++j){
        int   s = ssrc[base + j];
        float l = a1h + A[(size_t)s * 16 + 8 + h2] + sp[base + j] * w3h + sdv[base + j];
        l = (l >= 0.f) ? l : 0.2f * l;
        float alpha = __expf(l - mf) * inv;
        float2 v = *(const float2*)(V + (size_t)s * D_DIM + lane * 2);
        ax += alpha * v.x;
        ay += alpha * v.y;
    }
    float2 r; r.x = ax; r.y = ay;
    *(float2*)(agg + (size_t)node * D_DIM + lane * 2) = r;
}

// out = LN(agg@Wout + H@Wres + b_out + b_res) * gamma + beta; 4 rows/block, 128 thr
__global__ void k_final(const float* __restrict__ agg, const float* __restrict__ H,
                        const float* __restrict__ Wout, const float* __restrict__ Wres,
                        const float* __restrict__ b_out, const float* __restrict__ b_res,
                        const float* __restrict__ gamma, const float* __restrict__ beta,
                        float* __restrict__ out, int N){
    __shared__ float as_[4][D_DIM];
    __shared__ float hs[4][D_DIM];
    __shared__ float redS[2], redQ[2];
    int tid = threadIdx.x;
    int r0  = blockIdx.x * 4;
    #pragma unroll
    for (int r = 0; r < 4; ++r){
        int n = r0 + r;
        as_[r][tid] = (n < N) ? agg[(size_t)n * D_DIM + tid] : 0.f;
        hs[r][tid]  = (n < N) ? H[(size_t)n * D_DIM + tid]   : 0.f;
    }
    __syncthreads();
    float bias = b_out[tid] + b_res[tid];
    float acc[4] = {bias, bias, bias, bias};
    #pragma unroll 4
    for (int k = 0; k < D_DIM; ++k){
        float wo = Wout[k * D_DIM + tid];
        float wr = Wres[k * D_DIM + tid];
        #pragma unroll
        for (int r = 0; r < 4; ++r) acc[r] += as_[r][k] * wo + hs[r][k] * wr;
    }
    int lane = tid & 63, w = tid >> 6;
    float g = gamma[tid], b = beta[tid];
    #pragma unroll
    for (int r = 0; r < 4; ++r){
        float val = acc[r];
        float v = val, v2 = val * val;
        #pragma unroll
        for (int off = 32; off > 0; off >>= 1){
            v  += __shfl_down(v,  off);
            v2 += __shfl_down(v2, off);
        }
        if (lane == 0){ redS[w] = v; redQ[w] = v2; }
        __syncthreads();
        float mu = (redS[0] + redS[1]) * (1.f / 128.f);
        float ms = (redQ[0] + redQ[1]) * (1.f / 128.f);
        float rstd = rsqrtf(ms - mu * mu + 1e-5f);
        int n = r0 + r;
        if (n < N) out[(size_t)n * D_DIM + tid] = (val - mu) * rstd * g + b;
        __syncthreads();
    }
}

extern "C" void kernel_launch(void* const* d_in, const int* in_sizes, int n_in,
                              void* d_out, int out_size, void* d_ws, size_t ws_size,
                              hipStream_t stream){
    const float* H     = (const float*)d_in[0];
    const int*   ei    = (const int*)  d_in[1];
    const float* P     = (const float*)d_in[2];
    const float* det   = (const float*)d_in[3];
    const float* W1    = (const float*)d_in[4];
    const float* W2    = (const float*)d_in[5];
    const float* W3    = (const float*)d_in[6];
    const float* W4    = (const float*)d_in[7];
    const float* Wv    = (const float*)d_in[8];
    const float* Wout  = (const float*)d_in[9];
    const float* b_out = (const float*)d_in[10];
    const float* Wres  = (const float*)d_in[11];
    const float* b_res = (const float*)d_in[12];
    const float* gamma = (const float*)d_in[13];
    const float* beta  = (const float*)d_in[14];
    float* out = (float*)d_out;

    int N = in_sizes[0] / D_DIM;
    int E = in_sizes[2];
    int NB = (N + 255) / 256;

    float* ws = (float*)d_ws;
    size_t off = 0;
    float* M    = ws + off; off += 2048;
    float* w34  = ws + off; off += 8;
    float* A    = ws + off; off += (size_t)N * 16;
    float* V    = ws + off; off += (size_t)N * D_DIM;
    float* agg  = ws + off; off += (size_t)N * D_DIM;
    int* deg     = (int*)(ws + off); off += N;      // deg+cursor adjacent: one memset
    int* cursor  = (int*)(ws + off); off += N;
    int* offsets = (int*)(ws + off); off += N;
    int* bsum    = (int*)(ws + off); off += NB;
    int* boff    = (int*)(ws + off); off += NB;
    int* ssrc    = (int*)(ws + off); off += E;
    float* sp    = ws + off; off += E;
    float* sdv   = ws + off; off += E;

    hipMemsetAsync(deg, 0, (size_t)2 * N * sizeof(int), stream);

    k_prep<<<9, 256, 0, stream>>>(W1, W2, W3, W4, M, w34);
    k_A<<<(N * 16 + 255) / 256, 256, 0, stream>>>(H, M, A, N);
    k_rowgemm<<<(N + 3) / 4, 128, 0, stream>>>(H, Wv, V, N);

    k_deg<<<(E + 255) / 256, 256, 0, stream>>>(ei, deg, E);
    k_scan1<<<NB, 256, 0, stream>>>(deg, bsum, N);
    k_scan2<<<1, 256, 0, stream>>>(bsum, boff, NB);
    k_scan3<<<NB, 256, 0, stream>>>(deg, boff, offsets, N);
    k_scatter<<<(E + 255) / 256, 256, 0, stream>>>(ei, P, det, offsets, cursor,
                                                   ssrc, sp, sdv, E);
    k_agg<<<(N + 3) / 4, 256, 0, stream>>>(offsets, deg, ssrc, sp, sdv, A, w34, V, agg, N);

    k_final<<<(N + 3) / 4, 128, 0, stream>>>(agg, H, Wout, Wres, b_out, b_res,
                                             gamma, beta, out, N);
}